// Round 1
// 2442.552 us; speedup vs baseline: 1.2255x; 1.2255x over previous
//
#include <hip/hip_runtime.h>
#include <hip/hip_bf16.h>

typedef __bf16 bf16;
typedef __bf16 bf16x8 __attribute__((ext_vector_type(8)));
typedef float  f32x4 __attribute__((ext_vector_type(4)));

#define B_  16
#define S_  256
#define V_  32000
#define H_  1024

// ---------------- workspace layout (bytes) ----------------
// emb_frag : [2000 vtiles][32 kc][64][8] bf16 = 65,536,000
// Wh_frag  : [256 jtiles][32 kc][64][8] bf16  =  8,388,608
// Wx_frag  : same                              =  8,388,608
// xe_frag  : [256 rtiles][32 kc][64][8] bf16  =  8,388,608
// ys_frag  : [256 s][32 kc][64][8] bf16       =  8,388,608
// XcT      : [4096 j][4096 r] fp32            = 67,108,864
// flags    : 64 u32 (packed, 2 cache lines)   = 256
static const size_t OFF_WH  = 65536000;
static const size_t OFF_WX  = OFF_WH  + 8388608;
static const size_t OFF_XE  = OFF_WX  + 8388608;
static const size_t OFF_YS  = OFF_XE  + 8388608;
static const size_t OFF_XCT = OFF_YS  + 8388608;
static const size_t OFF_FLG = OFF_XCT + 67108864;

// Gather 8 consecutive fp32 from a row, convert to bf16, store as one 16B frag
// element for this lane. Fragment layout (both A and B operands of
// mfma_f32_16x16x32_bf16): lane holds Mrow/Nrow = lane&15, k = (lane>>4)*8 + e.
__device__ __forceinline__ void frag_gather_f32(const float* __restrict__ row,
                                                int k_off, bf16* __restrict__ unit,
                                                int lane) {
  const float* p = row + k_off + ((lane >> 4) * 8);
  const float4 lo = *reinterpret_cast<const float4*>(p);
  const float4 hi = *reinterpret_cast<const float4*>(p + 4);
  bf16x8 v;
  v[0] = (bf16)lo.x; v[1] = (bf16)lo.y; v[2] = (bf16)lo.z; v[3] = (bf16)lo.w;
  v[4] = (bf16)hi.x; v[5] = (bf16)hi.y; v[6] = (bf16)hi.z; v[7] = (bf16)hi.w;
  *reinterpret_cast<bf16x8*>(unit + lane * 8) = v;
}

__global__ void k_init(unsigned* flags) {
  flags[threadIdx.x] = 0u;   // <<<1,64>>>
}

// emb fp32 [V,H] -> emb_frag bf16 frag order. units = 2000*32 = 64000.
__global__ void k_convert_emb(const float* __restrict__ emb, bf16* __restrict__ emb_frag) {
  const int unit = blockIdx.x * 4 + (threadIdx.x >> 6);
  const int lane = threadIdx.x & 63;
  const int vt = unit >> 5;
  const int kc = unit & 31;
  const float* row = emb + (size_t)(vt * 16 + (lane & 15)) * H_;
  frag_gather_f32(row, kc * 32, emb_frag + (size_t)unit * 512, lane);
}

// W_i/f/o/c fp32 [H,2H] -> Wh_frag (k in [0,H)) and Wx_frag (k in [H,2H)).
// units = 2*8192 = 16384.
__global__ void k_convert_w(const float* __restrict__ Wi, const float* __restrict__ Wf,
                            const float* __restrict__ Wo, const float* __restrict__ Wc,
                            bf16* __restrict__ Wh_frag, bf16* __restrict__ Wx_frag) {
  const int unit = blockIdx.x * 4 + (threadIdx.x >> 6);
  const int lane = threadIdx.x & 63;
  const int which = unit >> 13;          // 0 = Wh, 1 = Wx
  const int u  = unit & 8191;
  const int jt = u >> 5;
  const int kc = u & 31;
  const int j  = jt * 16 + (lane & 15);  // global gate row, quadrant-ordered i,f,o,cc
  const int q  = j >> 10;
  const float* W = (q == 0) ? Wi : (q == 1) ? Wf : (q == 2) ? Wo : Wc;
  const float* row = W + (size_t)(j & 1023) * (2 * H_) + (which ? H_ : 0);
  bf16* dst = (which ? Wx_frag : Wh_frag) + (size_t)u * 512;
  frag_gather_f32(row, kc * 32, dst, lane);
}

// Embedding gather straight into frag order. Row r = s*16 + b; rtile == s.
// units = 256*32 = 8192.
__global__ void k_embed(const int* __restrict__ x, const float* __restrict__ emb,
                        bf16* __restrict__ xe_frag) {
  const int unit = blockIdx.x * 4 + (threadIdx.x >> 6);
  const int lane = threadIdx.x & 63;
  const int st = unit >> 5;
  const int kc = unit & 31;
  const int b  = lane & 15;
  const int tok = x[b * S_ + st];
  const float* row = emb + (size_t)tok * H_;
  frag_gather_f32(row, kc * 32, xe_frag + (size_t)unit * 512, lane);
}

// ---------------- shared 128x128x(K=1024) bf16 MFMA main loop ----------------
// A_frag/B_frag are frag-order [tile16][32 kc][1KB]. 256 threads, 4 waves 2x2,
// each wave 64x64 via 4x4 of 16x16x32 MFMAs. Staging = global_load_lds 16B.
__device__ __forceinline__ void gemm_main_128(const bf16* __restrict__ A_frag,
                                              const bf16* __restrict__ B_frag,
                                              int mtile, int ntile,
                                              bf16* smem, f32x4 acc[4][4]) {
  const int tid  = threadIdx.x;
  const int lane = tid & 63;
  const int w    = tid >> 6;
  const int wm   = w >> 1, wn = w & 1;
  bf16* Als = smem;           // [8][2][512] bf16 = 16KB
  bf16* Bls = smem + 8192;    // 16KB
  const f32x4 zero = {0.f, 0.f, 0.f, 0.f};
#pragma unroll
  for (int mi = 0; mi < 4; ++mi)
#pragma unroll
    for (int ni = 0; ni < 4; ++ni) acc[mi][ni] = zero;

  for (int it = 0; it < 16; ++it) {
    __syncthreads();  // previous compute done with LDS
#pragma unroll
    for (int c0 = 0; c0 < 8; ++c0) {
      const int c   = w * 8 + c0;        // 0..31: 16 A chunks then 16 B chunks
      const int isB = c >> 4;
      const int ci  = c & 15;
      const int i   = ci >> 1;
      const int kc  = ci & 1;
      const bf16* gsrc =
          (isB ? B_frag + (size_t)((ntile * 8 + i) * 32 + it * 2 + kc) * 512
               : A_frag + (size_t)((mtile * 8 + i) * 32 + it * 2 + kc) * 512) +
          lane * 8;
      bf16* ldst = (isB ? Bls : Als) + (i * 2 + kc) * 512;
      __builtin_amdgcn_global_load_lds(
          (const __attribute__((address_space(1))) void*)gsrc,
          (__attribute__((address_space(3))) void*)ldst, 16, 0, 0);
    }
    __syncthreads();  // barrier drains vmcnt -> LDS data ready
#pragma unroll
    for (int kc = 0; kc < 2; ++kc) {
      bf16x8 af[4], bfv[4];
#pragma unroll
      for (int i = 0; i < 4; ++i)
        af[i] = *reinterpret_cast<const bf16x8*>(Als + ((wm * 4 + i) * 2 + kc) * 512 + lane * 8);
#pragma unroll
      for (int i = 0; i < 4; ++i)
        bfv[i] = *reinterpret_cast<const bf16x8*>(Bls + ((wn * 4 + i) * 2 + kc) * 512 + lane * 8);
#pragma unroll
      for (int mi = 0; mi < 4; ++mi)
#pragma unroll
        for (int ni = 0; ni < 4; ++ni)
          acc[mi][ni] = __builtin_amdgcn_mfma_f32_16x16x32_bf16(af[mi], bfv[ni], acc[mi][ni], 0, 0, 0);
    }
  }
}

// Xc^T[j][r] = bias[j] + sum_k xe[r][k]*Wx[j][k].  grid (32 ntile, 32 mtile).
__global__ __launch_bounds__(256) void k_xc(const bf16* __restrict__ xe_frag,
                                            const bf16* __restrict__ Wx_frag,
                                            const float* __restrict__ bi, const float* __restrict__ bfp,
                                            const float* __restrict__ bo, const float* __restrict__ bc,
                                            float* __restrict__ XcT) {
  __shared__ bf16 smem[16384];
  const int ntile = blockIdx.x, mtile = blockIdx.y;
  f32x4 acc[4][4];
  gemm_main_128(xe_frag, Wx_frag, mtile, ntile, smem, acc);
  const int tid = threadIdx.x, lane = tid & 63, w = tid >> 6;
  const int wm = w >> 1, wn = w & 1;
  const int q = (ntile * 128) >> 10;  // 128-wide N tile never crosses a quadrant
  const float* bias = (q == 0) ? bi : (q == 1) ? bfp : (q == 2) ? bo : bc;
#pragma unroll
  for (int ni = 0; ni < 4; ++ni) {
    const int j = ntile * 128 + (wn * 4 + ni) * 16 + (lane & 15);
    const float bj = bias[j & 1023];
#pragma unroll
    for (int mi = 0; mi < 4; ++mi) {
      const int r0 = (mtile * 8 + wm * 4 + mi) * 16 + (lane >> 4) * 4;
      f32x4 v = acc[mi][ni];
      v[0] += bj; v[1] += bj; v[2] += bj; v[3] += bj;
      *reinterpret_cast<f32x4*>(XcT + (size_t)j * 4096 + r0) = v;
    }
  }
}

// Persistent LSTM recurrence. 64 blocks x 256 threads. Block owns h-cols
// [bid*16, bid*16+16); wave w = gate quadrant. This version:
//  - Wh fragments held in REGISTERS (32 x bf16x8 = 128 VGPR), loaded once.
//  - h[s-1] staged to LDS once per block (global_load_lds), shared by 4 waves.
//  - h written coalesced (LDS-assembled 512B contiguous half-chunk).
//  - cross-block sync: per-block packed release-store flags, wave0 polls all
//    64 flags with one coalesced load per round (no contended RMW chain).
//  - XcT gate inputs prefetched for s+1 while spinning on the barrier.
__global__ __launch_bounds__(256) void k_lstm(const bf16* __restrict__ Wh_frag,
                                              const float* __restrict__ XcT,
                                              bf16* __restrict__ ys_frag,
                                              float* __restrict__ out_hc,
                                              unsigned* __restrict__ flags) {
  const int bid  = blockIdx.x;
  const int tid  = threadIdx.x;
  const int lane = tid & 63;
  const int w    = tid >> 6;                 // gate quadrant
  __shared__ __align__(16) bf16 smemA[16384];   // 32KB: h[s-1] frag order
  __shared__ float gbuf[4][16][17];             // [quadrant][b][col], padded
  __shared__ __align__(16) bf16 hstage[256];    // block's 256 h values, chunk order
  const int cb   = tid & 15;                 // this thread's batch
  const int ccol = tid >> 4;                 // this thread's col (0..15)
  const int jq   = bid * 16 + ccol;          // h index / within-quadrant gate row
  float c_state = 0.f;

  // ---- preload B (Wh) fragments into registers: immune to per-step L2 inv ----
  const bf16* Wbase = Wh_frag + (size_t)(w * 64 + bid) * 32 * 512;
  bf16x8 breg[32];
#pragma unroll
  for (int kc = 0; kc < 32; ++kc)
    breg[kc] = *reinterpret_cast<const bf16x8*>(Wbase + kc * 512 + lane * 8);

  // ---- prefetch XcT for s=0 ----
  float xc0 = XcT[(size_t)(jq)        * 4096 + cb];
  float xc1 = XcT[(size_t)(1024 + jq) * 4096 + cb];
  float xc2 = XcT[(size_t)(2048 + jq) * 4096 + cb];
  float xc3 = XcT[(size_t)(3072 + jq) * 4096 + cb];

  for (int s = 0; s < S_; ++s) {
    f32x4 acc = {0.f, 0.f, 0.f, 0.f};
    if (s > 0) {
      // stage full h[s-1] (32KB) into LDS once; 8 rounds x 256 thr x 16B
      const bf16* Asrc = ys_frag + (size_t)(s - 1) * 16384;
#pragma unroll
      for (int r = 0; r < 8; ++r)
        __builtin_amdgcn_global_load_lds(
            (const __attribute__((address_space(1))) void*)(Asrc + r * 2048 + tid * 8),
            (__attribute__((address_space(3))) void*)(smemA + r * 2048 + tid * 8),
            16, 0, 0);
      __syncthreads();  // drains vmcnt -> LDS ready
      f32x4 p0 = {0.f,0.f,0.f,0.f}, p1 = p0, p2 = p0, p3 = p0;
#pragma unroll
      for (int kc = 0; kc < 32; kc += 4) {
        bf16x8 a0 = *reinterpret_cast<const bf16x8*>(smemA + (kc + 0) * 512 + lane * 8);
        bf16x8 a1 = *reinterpret_cast<const bf16x8*>(smemA + (kc + 1) * 512 + lane * 8);
        bf16x8 a2 = *reinterpret_cast<const bf16x8*>(smemA + (kc + 2) * 512 + lane * 8);
        bf16x8 a3 = *reinterpret_cast<const bf16x8*>(smemA + (kc + 3) * 512 + lane * 8);
        p0 = __builtin_amdgcn_mfma_f32_16x16x32_bf16(a0, breg[kc + 0], p0, 0, 0, 0);
        p1 = __builtin_amdgcn_mfma_f32_16x16x32_bf16(a1, breg[kc + 1], p1, 0, 0, 0);
        p2 = __builtin_amdgcn_mfma_f32_16x16x32_bf16(a2, breg[kc + 2], p2, 0, 0, 0);
        p3 = __builtin_amdgcn_mfma_f32_16x16x32_bf16(a3, breg[kc + 3], p3, 0, 0, 0);
      }
      f32x4 t01 = p0 + p1, t23 = p2 + p3;
      acc = t01 + t23;
    }
#pragma unroll
    for (int e = 0; e < 4; ++e)
      gbuf[w][(lane >> 4) * 4 + e][lane & 15] = acc[e];
    __syncthreads();

    const float g0 = gbuf[0][cb][ccol] + xc0;
    const float g1 = gbuf[1][cb][ccol] + xc1;
    const float g2 = gbuf[2][cb][ccol] + xc2;
    const float g3 = gbuf[3][cb][ccol] + xc3;
    const float ig = 1.f / (1.f + __expf(-g0));
    const float fg = 1.f / (1.f + __expf(-g1));
    const float og = 1.f / (1.f + __expf(-g2));
    c_state = fg * c_state + ig * tanhf(g3);
    const float h = og * tanhf(c_state);

    // assemble block's 512B contiguous half-chunk of ys_frag[s] in LDS:
    // element-in-chunk = lp*8+e, lp = cb+16*((jq>>3)&3), e = jq&7;
    // local index = (cb + 16*(ccol>>3))*8 + (ccol&7)
    hstage[(cb + 16 * (ccol >> 3)) * 8 + (ccol & 7)] = (bf16)h;
    if (s == S_ - 1) {
      out_hc[cb * H_ + jq]           = h;        // final h [B,H]
      out_hc[B_ * H_ + cb * H_ + jq] = c_state;  // final c [B,H]
    }
    __syncthreads();  // hstage ready; gbuf reads done

    // wave0 writes the block's contiguous 512B region (32 x 16B stores)
    if (tid < 32)
      *reinterpret_cast<bf16x8*>(ys_frag + ((size_t)s * 32 + (bid >> 1)) * 512 +
                                 (bid & 1) * 256 + tid * 8) =
          *reinterpret_cast<const bf16x8*>(hstage + tid * 8);

    if (s < S_ - 1) {
      // release store: wave0's s_waitcnt vmcnt(0) drains the ys stores (only
      // wave0 stored), buffer_wbl2 publishes them device-wide.
      if (tid == 0)
        __hip_atomic_store(&flags[bid], (unsigned)(s + 1), __ATOMIC_RELEASE,
                           __HIP_MEMORY_SCOPE_AGENT);
      // prefetch next step's XcT gate inputs: latency hides under the spin
      {
        const int r = (s + 1) * 16 + cb;
        xc0 = XcT[(size_t)(jq)        * 4096 + r];
        xc1 = XcT[(size_t)(1024 + jq) * 4096 + r];
        xc2 = XcT[(size_t)(2048 + jq) * 4096 + r];
        xc3 = XcT[(size_t)(3072 + jq) * 4096 + r];
      }
      if (tid < 64) {
        const unsigned target = (unsigned)(s + 1);
        unsigned v = __hip_atomic_load(&flags[tid], __ATOMIC_RELAXED,
                                       __HIP_MEMORY_SCOPE_AGENT);
        while (!__all((int)(v >= target))) {
          __builtin_amdgcn_s_sleep(1);
          v = __hip_atomic_load(&flags[tid], __ATOMIC_RELAXED,
                                __HIP_MEMORY_SCOPE_AGENT);
        }
        if (tid == 0)
          (void)__hip_atomic_load(&flags[0], __ATOMIC_ACQUIRE,
                                  __HIP_MEMORY_SCOPE_AGENT);
      }
      __syncthreads();
    }
  }
}

// logits[b][s][v] = fc_b[v] + sum_k ys[s][b][k]*emb[v][k]. grid (250 ntile, 32 mtile).
__global__ __launch_bounds__(256) void k_proj(const bf16* __restrict__ ys_frag,
                                              const bf16* __restrict__ emb_frag,
                                              const float* __restrict__ fcb,
                                              float* __restrict__ out) {
  __shared__ bf16 smem[16384];
  const int ntile = blockIdx.x, mtile = blockIdx.y;
  f32x4 acc[4][4];
  gemm_main_128(ys_frag, emb_frag, mtile, ntile, smem, acc);
  const int tid = threadIdx.x, lane = tid & 63, w = tid >> 6;
  const int wm = w >> 1, wn = w & 1;
  const size_t bstride = (size_t)S_ * V_;
#pragma unroll
  for (int ni = 0; ni < 4; ++ni) {
    const int v = ntile * 128 + (wn * 4 + ni) * 16 + (lane & 15);
    const float bv = fcb[v];
#pragma unroll
    for (int mi = 0; mi < 4; ++mi) {
      const int s  = mtile * 8 + wm * 4 + mi;
      const int b0 = (lane >> 4) * 4;
      float* po = out + (size_t)b0 * bstride + (size_t)s * V_ + v;
#pragma unroll
      for (int e = 0; e < 4; ++e)
        po[(size_t)e * bstride] = acc[mi][ni][e] + bv;
    }
  }
}

extern "C" void kernel_launch(void* const* d_in, const int* in_sizes, int n_in,
                              void* d_out, int out_size, void* d_ws, size_t ws_size,
                              hipStream_t stream) {
  const int*   x   = (const int*)  d_in[0];
  const float* emb = (const float*)d_in[1];
  const float* Wi  = (const float*)d_in[2];
  const float* bi  = (const float*)d_in[3];
  const float* Wf  = (const float*)d_in[4];
  const float* bfp = (const float*)d_in[5];
  const float* Wo  = (const float*)d_in[6];
  const float* bo  = (const float*)d_in[7];
  const float* Wc  = (const float*)d_in[8];
  const float* bc  = (const float*)d_in[9];
  const float* fcb = (const float*)d_in[10];

  char* ws = (char*)d_ws;
  bf16*     emb_frag = (bf16*)ws;
  bf16*     Wh_frag  = (bf16*)(ws + OFF_WH);
  bf16*     Wx_frag  = (bf16*)(ws + OFF_WX);
  bf16*     xe_frag  = (bf16*)(ws + OFF_XE);
  bf16*     ys_frag  = (bf16*)(ws + OFF_YS);
  float*    XcT      = (float*)(ws + OFF_XCT);
  unsigned* flags    = (unsigned*)(ws + OFF_FLG);

  float* out    = (float*)d_out;
  float* out_hc = out + (size_t)B_ * S_ * V_;

  k_init<<<1, 64, 0, stream>>>(flags);
  k_convert_emb<<<16000, 256, 0, stream>>>(emb, emb_frag);
  k_convert_w<<<4096, 256, 0, stream>>>(Wi, Wf, Wo, Wc, Wh_frag, Wx_frag);
  k_embed<<<2048, 256, 0, stream>>>(x, emb, xe_frag);
  k_xc<<<dim3(32, 32), 256, 0, stream>>>(xe_frag, Wx_frag, bi, bfp, bo, bc, XcT);
  k_lstm<<<64, 256, 0, stream>>>(Wh_frag, XcT, ys_frag, out_hc, flags);
  k_proj<<<dim3(250, 32), 256, 0, stream>>>(ys_frag, emb_frag, fcb, out);
}